// Round 16
// baseline (118.256 us; speedup 1.0000x reference)
//
#include <hip/hip_runtime.h>
#include <math.h>

#define B_ 64
#define Q_ 900
#define C_ 256
#define T_ 100
#define N_ 100            // min(Q,T)
#define BIGF 1.0e30f
#define ROWS_PER_LANE 15  // ceil(900/64) — greedy rescan striding
#define CHUNKS 25         // row-chunks for colmin partials (900/25 = 36 rows)
#define RPC 36            // rows per chunk

typedef unsigned int u32;
typedef unsigned long long ull;

// ---------------------------------------------------------------------------
// Key scheme:
//   u64 key  = ordf(v)<<18 | stale<<17 | row<<7 | t   (partials / rescan)
//   ikey = ~key (max semantics, identity 0)
// Greedy holds 32-bit split state: y = ~ordf(v) (dead = 0), id = stale|row|t.
// Pick order = lex(value, stale, row, t) == jnp.argmin flat order for fresh.
// ---------------------------------------------------------------------------
__device__ inline u32 hm_ordf(float v) {
    u32 u = __float_as_uint(v);
    return (u & 0x80000000u) ? ~u : (u | 0x80000000u);
}
__device__ inline ull hm_ikey(float v, int r, int t) {
    return ~(((ull)hm_ordf(v) << 18) | ((ull)(u32)r << 7) | (ull)(u32)t);
}

// ---------------------------------------------------------------------------
// Fused cost + column TOP-2 partials — F32 math mirroring the reference
// computation order (softmax: max-subtract / expf / sum / divide; boxes:
// xyxy, areas, inter, union, iou, enclosing, giou; cost = -prob + 5*l1
// - 2*giou). Replaces the f64 pipeline (f64-pipe-bound at 55 us).
// Justification: 13 rounds of evidence that pick gaps tolerate >=0.0625
// cost perturbation (np-f32's own error vs our exact values never flipped
// a pick); f32-vs-f32 discrepancy is ~1e-5.
// ---------------------------------------------------------------------------
__global__ __launch_bounds__(256) void hm_cost_colmin_f32(
    const float* __restrict__ logits,   // [B,Q,C]
    const float* __restrict__ pboxes,   // [B,Q,4] cxcywh
    const int*   __restrict__ tlabels,  // [B,T]
    const float* __restrict__ tboxes,   // [B,T,4] cxcywh
    float* __restrict__ cost,           // [B,Q,T]
    ull* __restrict__ part)             // [B,CHUNKS,T,2] inverted top-2 keys
{
    int bc   = blockIdx.x;
    int b    = bc / CHUNKS;
    int c    = bc % CHUNKS;
    int lane = threadIdx.x & 63;
    int wid  = threadIdx.x >> 6;        // 0..3
    int r0   = c * RPC;

    __shared__ float s_exp[4][C_];      // 4 KB
    __shared__ ull   s_part[4][128][2]; // 8 KB

    int ta = lane, tb = 64 + lane;
    bool hb = (tb < T_);
    int laba = tlabels[b * T_ + ta];
    int labb = hb ? tlabels[b * T_ + tb] : 0;
    const float* tba = tboxes + ((size_t)b * T_ + ta) * 4;
    const float* tbb = tboxes + ((size_t)b * T_ + (hb ? tb : 0)) * 4;
    float tcxa = tba[0], tcya = tba[1], twa = tba[2], tha = tba[3];
    float tcxb = tbb[0], tcyb = tbb[1], twb = tbb[2], thb_ = tbb[3];
    float txa1 = tcxa - 0.5f * twa, tya1 = tcya - 0.5f * tha;
    float txa2 = tcxa + 0.5f * twa, tya2 = tcya + 0.5f * tha;
    float txb1 = tcxb - 0.5f * twb, tyb1 = tcyb - 0.5f * thb_;
    float txb2 = tcxb + 0.5f * twb, tyb2 = tcyb + 0.5f * thb_;
    float area2a = fmaxf(txa2 - txa1, 0.0f) * fmaxf(tya2 - tya1, 0.0f);
    float area2b = fmaxf(txb2 - txb1, 0.0f) * fmaxf(tyb2 - tyb1, 0.0f);

    ull ka1 = 0ull, ka2 = 0ull;
    ull kb1 = 0ull, kb2 = 0ull;

    for (int r = r0 + wid; r < r0 + RPC; r += 4) {
        int bq = b * Q_ + r;

        const float* row = logits + (size_t)bq * C_;
        float v[4];
        float m = -INFINITY;
#pragma unroll
        for (int i = 0; i < 4; ++i) {
            v[i] = row[lane + 64 * i];
            m = fmaxf(m, v[i]);
        }
#pragma unroll
        for (int off = 32; off >= 1; off >>= 1)
            m = fmaxf(m, __shfl_xor(m, off, 64));

        float e[4];
        float s = 0.0f;
#pragma unroll
        for (int i = 0; i < 4; ++i) {
            e[i] = expf(v[i] - m);
            s += e[i];
        }
#pragma unroll
        for (int off = 32; off >= 1; off >>= 1)
            s += __shfl_xor(s, off, 64);

#pragma unroll
        for (int i = 0; i < 4; ++i)
            s_exp[wid][lane + 64 * i] = e[i];

        const float* pb = pboxes + (size_t)bq * 4;
        float pcx = pb[0], pcy = pb[1], pw = pb[2], ph = pb[3];
        float px1 = pcx - 0.5f * pw, py1 = pcy - 0.5f * ph;
        float px2 = pcx + 0.5f * pw, py2 = pcy + 0.5f * ph;
        float area1 = fmaxf(px2 - px1, 0.0f) * fmaxf(py2 - py1, 0.0f);

        {
            float prob = s_exp[wid][laba] / s;
            float l1 = fabsf(pcx - tcxa) + fabsf(pcy - tcya) + fabsf(pw - twa) + fabsf(ph - tha);
            float iw = fmaxf(fminf(px2, txa2) - fmaxf(px1, txa1), 0.0f);
            float ih = fmaxf(fminf(py2, tya2) - fmaxf(py1, tya1), 0.0f);
            float inter = iw * ih;
            float uni = area1 + area2a - inter;
            float iou = inter / fmaxf(uni, 1e-6f);
            float ew = fmaxf(fmaxf(px2, txa2) - fminf(px1, txa1), 0.0f);
            float eh = fmaxf(fmaxf(py2, tya2) - fminf(py1, tya1), 0.0f);
            float earea = ew * eh;
            float giou = iou - (earea - uni) / fmaxf(earea, 1e-6f);
            float cf = -prob + 5.0f * l1 - 2.0f * giou;
            cost[(size_t)bq * T_ + ta] = cf;
            ull kk = hm_ikey(cf, r, ta);
            if (kk > ka1) { ka2 = ka1; ka1 = kk; }
            else if (kk > ka2) ka2 = kk;
        }
        if (hb) {
            float prob = s_exp[wid][labb] / s;
            float l1 = fabsf(pcx - tcxb) + fabsf(pcy - tcyb) + fabsf(pw - twb) + fabsf(ph - thb_);
            float iw = fmaxf(fminf(px2, txb2) - fmaxf(px1, txb1), 0.0f);
            float ih = fmaxf(fminf(py2, tyb2) - fmaxf(py1, tyb1), 0.0f);
            float inter = iw * ih;
            float uni = area1 + area2b - inter;
            float iou = inter / fmaxf(uni, 1e-6f);
            float ew = fmaxf(fmaxf(px2, txb2) - fminf(px1, txb1), 0.0f);
            float eh = fmaxf(fmaxf(py2, tyb2) - fminf(py1, tyb1), 0.0f);
            float earea = ew * eh;
            float giou = iou - (earea - uni) / fmaxf(earea, 1e-6f);
            float cf = -prob + 5.0f * l1 - 2.0f * giou;
            cost[(size_t)bq * T_ + tb] = cf;
            ull kk = hm_ikey(cf, r, tb);
            if (kk > kb1) { kb2 = kb1; kb1 = kk; }
            else if (kk > kb2) kb2 = kk;
        }
    }

    s_part[wid][lane][0]      = ka1;
    s_part[wid][lane][1]      = ka2;
    s_part[wid][64 + lane][0] = kb1;
    s_part[wid][64 + lane][1] = kb2;
    __syncthreads();
    int tid = threadIdx.x;
    if (tid < T_) {
        ull b1 = 0ull, b2 = 0ull;
#pragma unroll
        for (int w = 0; w < 4; ++w) {
#pragma unroll
            for (int j = 0; j < 2; ++j) {
                ull cc = s_part[w][tid][j];
                if (cc > b1) { b2 = b1; b1 = cc; }
                else if (cc > b2) b2 = cc;
            }
        }
        ull* dst = part + (((size_t)b * CHUNKS + c) * T_ + tid) * 2;
        dst[0] = b1;
        dst[1] = b2;
    }
}

// ---------------------------------------------------------------------------
// DPP helpers.
// ---------------------------------------------------------------------------
__device__ inline u32 hm_umax32(u32 a, u32 b) { return a > b ? a : b; }

template <int CTRL>
__device__ inline u32 hm_stage(u32 x) {
    u32 p = (u32)__builtin_amdgcn_update_dpp(0, (int)x, CTRL, 0xF, 0xF, false);
    return x > p ? x : p;
}

template <int CTRL>
__device__ inline ull hm_dpp64(ull x) {
    u32 lo = (u32)x, hi = (u32)(x >> 32);
    lo = (u32)__builtin_amdgcn_update_dpp(0, (int)lo, CTRL, 0xF, 0xF, false);
    hi = (u32)__builtin_amdgcn_update_dpp(0, (int)hi, CTRL, 0xF, 0xF, false);
    return ((ull)hi << 32) | lo;
}
__device__ inline ull hm_wave_max_full64(ull x) {    // rare rescan path only
    ull p;
    p = hm_dpp64<0x111>(x); x = (p > x) ? p : x;
    p = hm_dpp64<0x112>(x); x = (p > x) ? p : x;
    p = hm_dpp64<0x114>(x); x = (p > x) ? p : x;
    p = hm_dpp64<0x118>(x); x = (p > x) ? p : x;
    p = hm_dpp64<0x142>(x); x = (p > x) ? p : x;
    p = hm_dpp64<0x143>(x); x = (p > x) ? p : x;
    u32 lo = (u32)__builtin_amdgcn_readlane((int)(u32)x, 63);
    u32 hi = (u32)__builtin_amdgcn_readlane((int)(u32)(x >> 32), 63);
    return ((ull)hi << 32) | lo;
}

// ---------------------------------------------------------------------------
// Greedy: TWO BATCHES PER WAVE (32 blocks), chains hand-interleaved so the
// two batches' independent DPP reductions fill each other's latency bubbles.
// Per-batch round = R13's proven branch-free two-phase (32-bit):
//   phase1: 6-stage DPP max of y=~ordf -> winner value (readlane 63)
//   phase2: 6-stage DPP max of ~id among value-ties -> winner id
//   stale winner (bit17) -> u64 column rescan for that batch, retry its k.
// ---------------------------------------------------------------------------
__global__ __launch_bounds__(64) void hm_greedy_g2(
    const float* __restrict__ cost,     // [B,Q,T]
    const ull* __restrict__ part,       // [B,CHUNKS,T,2]
    float* __restrict__ out_src,        // [B,N]
    float* __restrict__ out_tgt)        // [B,N]
{
    int bp = blockIdx.x;                // 0..31
    int b0 = bp * 2, b1 = bp * 2 + 1;
    int l = threadIdx.x;                // 0..63
    const float* C0 = cost + (size_t)b0 * Q_ * T_;
    const float* C1 = cost + (size_t)b1 * Q_ * T_;

    int  t0 = l, t1 = 64 + l;
    bool a1 = (t1 < T_);

    // ---- phase 0: fold chunk top-2 partials for both batches ----
    ull pA1_0 = 0ull, pA2_0 = 0ull, pB1_0 = 0ull, pB2_0 = 0ull; // batch0 colA/colB
    ull pA1_1 = 0ull, pA2_1 = 0ull, pB1_1 = 0ull, pB2_1 = 0ull; // batch1
#pragma unroll
    for (int c = 0; c < CHUNKS; ++c) {
        const ull* q0 = part + (((size_t)b0 * CHUNKS + c) * T_ + t0) * 2;
        const ull* q1 = part + (((size_t)b1 * CHUNKS + c) * T_ + t0) * 2;
#pragma unroll
        for (int j = 0; j < 2; ++j) {
            ull cc = q0[j];
            if (cc > pA1_0) { pA2_0 = pA1_0; pA1_0 = cc; } else if (cc > pA2_0) pA2_0 = cc;
            ull dd = q1[j];
            if (dd > pA1_1) { pA2_1 = pA1_1; pA1_1 = dd; } else if (dd > pA2_1) pA2_1 = dd;
        }
        if (a1) {
            const ull* r0p = part + (((size_t)b0 * CHUNKS + c) * T_ + t1) * 2;
            const ull* r1p = part + (((size_t)b1 * CHUNKS + c) * T_ + t1) * 2;
#pragma unroll
            for (int j = 0; j < 2; ++j) {
                ull cc = r0p[j];
                if (cc > pB1_0) { pB2_0 = pB1_0; pB1_0 = cc; } else if (cc > pB2_0) pB2_0 = cc;
                ull dd = r1p[j];
                if (dd > pB1_1) { pB2_1 = pB1_1; pB1_1 = dd; } else if (dd > pB2_1) pB2_1 = dd;
            }
        }
    }

    // split to (y = ~ordf, id) — batch 0
    u32 ya0  = ~((u32)((~pA1_0) >> 18)), ida0  = (u32)(~pA1_0) & 0x3FFFFu;
    u32 y2a0 = ~((u32)((~pA2_0) >> 18)), id2a0 = (u32)(~pA2_0) & 0x3FFFFu;
    u32 yb0  = a1 ? ~((u32)((~pB1_0) >> 18)) : 0u;
    u32 idb0 = a1 ? ((u32)(~pB1_0) & 0x3FFFFu) : 0x3FFFFu;
    u32 y2b0 = a1 ? ~((u32)((~pB2_0) >> 18)) : 0u;
    u32 id2b0 = a1 ? ((u32)(~pB2_0) & 0x3FFFFu) : 0x3FFFFu;
    // batch 1
    u32 ya1  = ~((u32)((~pA1_1) >> 18)), ida1  = (u32)(~pA1_1) & 0x3FFFFu;
    u32 y2a1 = ~((u32)((~pA2_1) >> 18)), id2a1 = (u32)(~pA2_1) & 0x3FFFFu;
    u32 yb1  = a1 ? ~((u32)((~pB1_1) >> 18)) : 0u;
    u32 idb1 = a1 ? ((u32)(~pB1_1) & 0x3FFFFu) : 0x3FFFFu;
    u32 y2b1 = a1 ? ~((u32)((~pB2_1) >> 18)) : 0u;
    u32 id2b1 = a1 ? ((u32)(~pB2_1) & 0x3FFFFu) : 0x3FFFFu;

    unsigned rem0 = 0u, rem1 = 0u;
    u32 pk00 = 0u, pk01 = 0u, pk10 = 0u, pk11 = 0u;
    int k0 = 0, k1 = 0;

    while (k0 < N_ || k1 < N_) {
        // ---- phase 1 (both batches, interleaved stages)
        u32 x0 = (k0 < N_) ? hm_umax32(ya0, yb0) : 0u;
        u32 x1 = (k1 < N_) ? hm_umax32(ya1, yb1) : 0u;
        x0 = hm_stage<0x111>(x0); x1 = hm_stage<0x111>(x1);
        x0 = hm_stage<0x112>(x0); x1 = hm_stage<0x112>(x1);
        x0 = hm_stage<0x114>(x0); x1 = hm_stage<0x114>(x1);
        x0 = hm_stage<0x118>(x0); x1 = hm_stage<0x118>(x1);
        x0 = hm_stage<0x142>(x0); x1 = hm_stage<0x142>(x1);
        x0 = hm_stage<0x143>(x0); x1 = hm_stage<0x143>(x1);
        u32 winy0 = (u32)__builtin_amdgcn_readlane((int)x0, 63);
        u32 winy1 = (u32)__builtin_amdgcn_readlane((int)x1, 63);

        // ---- phase 2 (both batches, interleaved stages)
        u32 za0 = (ya0 == winy0) ? ~ida0 : 0u;
        u32 zb0 = (yb0 == winy0) ? ~idb0 : 0u;
        u32 z0 = hm_umax32(za0, zb0);
        u32 za1 = (ya1 == winy1) ? ~ida1 : 0u;
        u32 zb1 = (yb1 == winy1) ? ~idb1 : 0u;
        u32 z1 = hm_umax32(za1, zb1);
        z0 = hm_stage<0x111>(z0); z1 = hm_stage<0x111>(z1);
        z0 = hm_stage<0x112>(z0); z1 = hm_stage<0x112>(z1);
        z0 = hm_stage<0x114>(z0); z1 = hm_stage<0x114>(z1);
        z0 = hm_stage<0x118>(z0); z1 = hm_stage<0x118>(z1);
        z0 = hm_stage<0x142>(z0); z1 = hm_stage<0x142>(z1);
        z0 = hm_stage<0x143>(z0); z1 = hm_stage<0x143>(z1);
        u32 winid0 = (~(u32)__builtin_amdgcn_readlane((int)z0, 63)) & 0x3FFFFu;
        u32 winid1 = (~(u32)__builtin_amdgcn_readlane((int)z1, 63)) & 0x3FFFFu;

        // ================= batch 0 =================
        if (k0 < N_) {
            int t = (int)(winid0 & 127u);
            int q = (int)((winid0 >> 7) & 1023u);
            if (winid0 & 0x20000u) {
                // rescan column t of batch 0, retry k0
                ull b1k = 0ull, b2k = 0ull;
#pragma unroll
                for (int i = 0; i < ROWS_PER_LANE; ++i) {
                    int r = l + 64 * i;
                    bool ok = (r < Q_) && !((rem0 >> i) & 1u);
                    float v = ok ? C0[(size_t)r * T_ + t] : BIGF;
                    ull ik = ok ? hm_ikey(v, r, t) : 0ull;
                    if (ik > b1k) { b2k = b1k; b1k = ik; }
                    else if (ik > b2k) b2k = ik;
                }
                ull w1 = hm_wave_max_full64(b1k);
                ull alt = (b1k == w1) ? b2k : b1k;
                ull w2 = hm_wave_max_full64(alt);
                if (t0 == t) {
                    ya0  = ~((u32)((~w1) >> 18)); ida0  = (u32)(~w1) & 0x3FFFFu;
                    y2a0 = ~((u32)((~w2) >> 18)); id2a0 = (u32)(~w2) & 0x3FFFFu;
                }
                if (t1 == t) {
                    yb0  = ~((u32)((~w1) >> 18)); idb0  = (u32)(~w1) & 0x3FFFFu;
                    y2b0 = ~((u32)((~w2) >> 18)); id2b0 = (u32)(~w2) & 0x3FFFFu;
                }
            } else {
                u32 qt = winid0 & 0x1FFFFu;
                if (k0 < 64) { if (l == k0)        pk00 = qt; }
                else         { if (l == (k0 & 63)) pk01 = qt; }
                if ((q & 63) == l) rem0 |= 1u << (q >> 6);
                {
                    bool die1 = (((ida0  >> 7) & 1023u) == (u32)q);
                    bool die2 = (((id2a0 >> 7) & 1023u) == (u32)q);
                    u32 nya  = die1 ? y2a0  : ya0;
                    u32 nida = die1 ? id2a0 : ida0;
                    u32 nid2 = (die1 || die2) ? (id2a0 | 0x20000u) : id2a0;
                    bool kill = (t0 == t);
                    ya0   = kill ? 0u       : nya;
                    ida0  = kill ? 0x3FFFFu : nida;
                    y2a0  = kill ? 0u       : y2a0;
                    id2a0 = kill ? 0x3FFFFu : nid2;
                }
                {
                    bool die1 = (((idb0  >> 7) & 1023u) == (u32)q);
                    bool die2 = (((id2b0 >> 7) & 1023u) == (u32)q);
                    u32 nyb  = die1 ? y2b0  : yb0;
                    u32 nidb = die1 ? id2b0 : idb0;
                    u32 nid2 = (die1 || die2) ? (id2b0 | 0x20000u) : id2b0;
                    bool kill = (t1 == t);
                    yb0   = kill ? 0u       : nyb;
                    idb0  = kill ? 0x3FFFFu : nidb;
                    y2b0  = kill ? 0u       : y2b0;
                    id2b0 = kill ? 0x3FFFFu : nid2;
                }
                ++k0;
            }
        }

        // ================= batch 1 =================
        if (k1 < N_) {
            int t = (int)(winid1 & 127u);
            int q = (int)((winid1 >> 7) & 1023u);
            if (winid1 & 0x20000u) {
                ull b1k = 0ull, b2k = 0ull;
#pragma unroll
                for (int i = 0; i < ROWS_PER_LANE; ++i) {
                    int r = l + 64 * i;
                    bool ok = (r < Q_) && !((rem1 >> i) & 1u);
                    float v = ok ? C1[(size_t)r * T_ + t] : BIGF;
                    ull ik = ok ? hm_ikey(v, r, t) : 0ull;
                    if (ik > b1k) { b2k = b1k; b1k = ik; }
                    else if (ik > b2k) b2k = ik;
                }
                ull w1 = hm_wave_max_full64(b1k);
                ull alt = (b1k == w1) ? b2k : b1k;
                ull w2 = hm_wave_max_full64(alt);
                if (t0 == t) {
                    ya1  = ~((u32)((~w1) >> 18)); ida1  = (u32)(~w1) & 0x3FFFFu;
                    y2a1 = ~((u32)((~w2) >> 18)); id2a1 = (u32)(~w2) & 0x3FFFFu;
                }
                if (t1 == t) {
                    yb1  = ~((u32)((~w1) >> 18)); idb1  = (u32)(~w1) & 0x3FFFFu;
                    y2b1 = ~((u32)((~w2) >> 18)); id2b1 = (u32)(~w2) & 0x3FFFFu;
                }
            } else {
                u32 qt = winid1 & 0x1FFFFu;
                if (k1 < 64) { if (l == k1)        pk10 = qt; }
                else         { if (l == (k1 & 63)) pk11 = qt; }
                if ((q & 63) == l) rem1 |= 1u << (q >> 6);
                {
                    bool die1 = (((ida1  >> 7) & 1023u) == (u32)q);
                    bool die2 = (((id2a1 >> 7) & 1023u) == (u32)q);
                    u32 nya  = die1 ? y2a1  : ya1;
                    u32 nida = die1 ? id2a1 : ida1;
                    u32 nid2 = (die1 || die2) ? (id2a1 | 0x20000u) : id2a1;
                    bool kill = (t0 == t);
                    ya1   = kill ? 0u       : nya;
                    ida1  = kill ? 0x3FFFFu : nida;
                    y2a1  = kill ? 0u       : y2a1;
                    id2a1 = kill ? 0x3FFFFu : nid2;
                }
                {
                    bool die1 = (((idb1  >> 7) & 1023u) == (u32)q);
                    bool die2 = (((id2b1 >> 7) & 1023u) == (u32)q);
                    u32 nyb  = die1 ? y2b1  : yb1;
                    u32 nidb = die1 ? id2b1 : idb1;
                    u32 nid2 = (die1 || die2) ? (id2b1 | 0x20000u) : id2b1;
                    bool kill = (t1 == t);
                    yb1   = kill ? 0u       : nyb;
                    idb1  = kill ? 0x3FFFFu : nidb;
                    y2b1  = kill ? 0u       : y2b1;
                    id2b1 = kill ? 0x3FFFFu : nid2;
                }
                ++k1;
            }
        }
    }

    // ---- coalesced final stores
    {
        float* os = out_src + b0 * N_;
        float* ot = out_tgt + b0 * N_;
        os[l] = (float)(pk00 >> 7);
        ot[l] = (float)(pk00 & 127u);
        if (l < N_ - 64) {
            os[64 + l] = (float)(pk01 >> 7);
            ot[64 + l] = (float)(pk01 & 127u);
        }
    }
    {
        float* os = out_src + b1 * N_;
        float* ot = out_tgt + b1 * N_;
        os[l] = (float)(pk10 >> 7);
        ot[l] = (float)(pk10 & 127u);
        if (l < N_ - 64) {
            os[64 + l] = (float)(pk11 >> 7);
            ot[64 + l] = (float)(pk11 & 127u);
        }
    }
}

// ---------------------------------------------------------------------------
extern "C" void kernel_launch(void* const* d_in, const int* in_sizes, int n_in,
                              void* d_out, int out_size, void* d_ws, size_t ws_size,
                              hipStream_t stream)
{
    const float* pred_logits = (const float*)d_in[0];  // [B,Q,C]
    const float* pred_boxes  = (const float*)d_in[1];  // [B,Q,4]
    const int*   tgt_labels  = (const int*)d_in[2];    // [B,T]
    const float* tgt_boxes   = (const float*)d_in[3];  // [B,T,4]

    float* out_cost = (float*)d_out;                       // [B,Q,T]
    float* out_src  = out_cost + (size_t)B_ * Q_ * T_;     // [B,N]
    float* out_tgt  = out_src  + (size_t)B_ * N_;          // [B,N]

    ull* part = (ull*)d_ws;                                // [B,CHUNKS,T,2] 2.56 MB

    // 1: fused softmax + cost + column top-2 partials — f32 pipeline
    hm_cost_colmin_f32<<<B_ * CHUNKS, 256, 0, stream>>>(pred_logits, pred_boxes,
                                                        tgt_labels, tgt_boxes,
                                                        out_cost, part);

    // 2: greedy — 2 batches per wave, interleaved DPP chains
    hm_greedy_g2<<<B_ / 2, 64, 0, stream>>>(out_cost, part, out_src, out_tgt);
}

// Round 17
// 104.550 us; speedup vs baseline: 1.1311x; 1.1311x over previous
//
#include <hip/hip_runtime.h>
#include <math.h>

#define B_ 64
#define Q_ 900
#define C_ 256
#define T_ 100
#define N_ 100            // min(Q,T)
#define BIGF 1.0e30f
#define ROWS_PER_LANE 15  // ceil(900/64) — rescan striding
#define CHUNKS 25         // row-chunks for colmin partials
#define RPC 36            // rows per chunk
#define MAXK 0xFFFFFFFFFFFFFFFFull

typedef unsigned int u32;
typedef unsigned long long ull;

// ---------------------------------------------------------------------------
// Keys: plain key = ordf(v)<<18 | row<<7 | t  (bit17 unused=0). Unique per
// column (t in low bits). Ascending u64 order == lex(value, q, t) == exact
// jnp.argmin flat order. part[] stores INVERTED keys (~key, max semantics).
// ---------------------------------------------------------------------------
__device__ inline u32 hm_ordf(float v) {
    u32 u = __float_as_uint(v);
    return (u & 0x80000000u) ? ~u : (u | 0x80000000u);
}
__device__ inline ull hm_ikey(float v, int r, int t) {
    return ~(((ull)hm_ordf(v) << 18) | ((ull)(u32)r << 7) | (ull)(u32)t);
}

// ---------------------------------------------------------------------------
// Fused cost + column TOP-2 partials — EXACT copy of R16's f32 kernel
// (bit-identical cost matrix; absmax 0.015625 verified).
// ---------------------------------------------------------------------------
__global__ __launch_bounds__(256) void hm_cost_colmin_f32(
    const float* __restrict__ logits,   // [B,Q,C]
    const float* __restrict__ pboxes,   // [B,Q,4] cxcywh
    const int*   __restrict__ tlabels,  // [B,T]
    const float* __restrict__ tboxes,   // [B,T,4] cxcywh
    float* __restrict__ cost,           // [B,Q,T]
    ull* __restrict__ part)             // [B,CHUNKS,T,2] inverted top-2 keys
{
    int bc   = blockIdx.x;
    int b    = bc / CHUNKS;
    int c    = bc % CHUNKS;
    int lane = threadIdx.x & 63;
    int wid  = threadIdx.x >> 6;        // 0..3
    int r0   = c * RPC;

    __shared__ float s_exp[4][C_];      // 4 KB
    __shared__ ull   s_part[4][128][2]; // 8 KB

    int ta = lane, tb = 64 + lane;
    bool hb = (tb < T_);
    int laba = tlabels[b * T_ + ta];
    int labb = hb ? tlabels[b * T_ + tb] : 0;
    const float* tba = tboxes + ((size_t)b * T_ + ta) * 4;
    const float* tbb = tboxes + ((size_t)b * T_ + (hb ? tb : 0)) * 4;
    float tcxa = tba[0], tcya = tba[1], twa = tba[2], tha = tba[3];
    float tcxb = tbb[0], tcyb = tbb[1], twb = tbb[2], thb_ = tbb[3];
    float txa1 = tcxa - 0.5f * twa, tya1 = tcya - 0.5f * tha;
    float txa2 = tcxa + 0.5f * twa, tya2 = tcya + 0.5f * tha;
    float txb1 = tcxb - 0.5f * twb, tyb1 = tcyb - 0.5f * thb_;
    float txb2 = tcxb + 0.5f * twb, tyb2 = tcyb + 0.5f * thb_;
    float area2a = fmaxf(txa2 - txa1, 0.0f) * fmaxf(tya2 - tya1, 0.0f);
    float area2b = fmaxf(txb2 - txb1, 0.0f) * fmaxf(tyb2 - tyb1, 0.0f);

    ull ka1 = 0ull, ka2 = 0ull;
    ull kb1 = 0ull, kb2 = 0ull;

    for (int r = r0 + wid; r < r0 + RPC; r += 4) {
        int bq = b * Q_ + r;

        const float* row = logits + (size_t)bq * C_;
        float v[4];
        float m = -INFINITY;
#pragma unroll
        for (int i = 0; i < 4; ++i) {
            v[i] = row[lane + 64 * i];
            m = fmaxf(m, v[i]);
        }
#pragma unroll
        for (int off = 32; off >= 1; off >>= 1)
            m = fmaxf(m, __shfl_xor(m, off, 64));

        float e[4];
        float s = 0.0f;
#pragma unroll
        for (int i = 0; i < 4; ++i) {
            e[i] = expf(v[i] - m);
            s += e[i];
        }
#pragma unroll
        for (int off = 32; off >= 1; off >>= 1)
            s += __shfl_xor(s, off, 64);

#pragma unroll
        for (int i = 0; i < 4; ++i)
            s_exp[wid][lane + 64 * i] = e[i];

        const float* pb = pboxes + (size_t)bq * 4;
        float pcx = pb[0], pcy = pb[1], pw = pb[2], ph = pb[3];
        float px1 = pcx - 0.5f * pw, py1 = pcy - 0.5f * ph;
        float px2 = pcx + 0.5f * pw, py2 = pcy + 0.5f * ph;
        float area1 = fmaxf(px2 - px1, 0.0f) * fmaxf(py2 - py1, 0.0f);

        {
            float prob = s_exp[wid][laba] / s;
            float l1 = fabsf(pcx - tcxa) + fabsf(pcy - tcya) + fabsf(pw - twa) + fabsf(ph - tha);
            float iw = fmaxf(fminf(px2, txa2) - fmaxf(px1, txa1), 0.0f);
            float ih = fmaxf(fminf(py2, tya2) - fmaxf(py1, tya1), 0.0f);
            float inter = iw * ih;
            float uni = area1 + area2a - inter;
            float iou = inter / fmaxf(uni, 1e-6f);
            float ew = fmaxf(fmaxf(px2, txa2) - fminf(px1, txa1), 0.0f);
            float eh = fmaxf(fmaxf(py2, tya2) - fminf(py1, tya1), 0.0f);
            float earea = ew * eh;
            float giou = iou - (earea - uni) / fmaxf(earea, 1e-6f);
            float cf = -prob + 5.0f * l1 - 2.0f * giou;
            cost[(size_t)bq * T_ + ta] = cf;
            ull kk = hm_ikey(cf, r, ta);
            if (kk > ka1) { ka2 = ka1; ka1 = kk; }
            else if (kk > ka2) ka2 = kk;
        }
        if (hb) {
            float prob = s_exp[wid][labb] / s;
            float l1 = fabsf(pcx - tcxb) + fabsf(pcy - tcyb) + fabsf(pw - twb) + fabsf(ph - thb_);
            float iw = fmaxf(fminf(px2, txb2) - fmaxf(px1, txb1), 0.0f);
            float ih = fmaxf(fminf(py2, tyb2) - fmaxf(py1, tyb1), 0.0f);
            float inter = iw * ih;
            float uni = area1 + area2b - inter;
            float iou = inter / fmaxf(uni, 1e-6f);
            float ew = fmaxf(fmaxf(px2, txb2) - fminf(px1, txb1), 0.0f);
            float eh = fmaxf(fmaxf(py2, tyb2) - fminf(py1, tyb1), 0.0f);
            float earea = ew * eh;
            float giou = iou - (earea - uni) / fmaxf(earea, 1e-6f);
            float cf = -prob + 5.0f * l1 - 2.0f * giou;
            cost[(size_t)bq * T_ + tb] = cf;
            ull kk = hm_ikey(cf, r, tb);
            if (kk > kb1) { kb2 = kb1; kb1 = kk; }
            else if (kk > kb2) kb2 = kk;
        }
    }

    s_part[wid][lane][0]      = ka1;
    s_part[wid][lane][1]      = ka2;
    s_part[wid][64 + lane][0] = kb1;
    s_part[wid][64 + lane][1] = kb2;
    __syncthreads();
    int tid = threadIdx.x;
    if (tid < T_) {
        ull b1 = 0ull, b2 = 0ull;
#pragma unroll
        for (int w = 0; w < 4; ++w) {
#pragma unroll
            for (int j = 0; j < 2; ++j) {
                ull cc = s_part[w][tid][j];
                if (cc > b1) { b2 = b1; b1 = cc; }
                else if (cc > b2) b2 = cc;
            }
        }
        ull* dst = part + (((size_t)b * CHUNKS + c) * T_ + tid) * 2;
        dst[0] = b1;
        dst[1] = b2;
    }
}

// ---------------------------------------------------------------------------
// u64 DPP max chain (rare paths only).
// ---------------------------------------------------------------------------
template <int CTRL>
__device__ inline ull hm_dpp64(ull x) {
    u32 lo = (u32)x, hi = (u32)(x >> 32);
    lo = (u32)__builtin_amdgcn_update_dpp(0, (int)lo, CTRL, 0xF, 0xF, false);
    hi = (u32)__builtin_amdgcn_update_dpp(0, (int)hi, CTRL, 0xF, 0xF, false);
    return ((ull)hi << 32) | lo;
}
__device__ inline ull hm_wave_max_full64(ull x) {
    ull p;
    p = hm_dpp64<0x111>(x); x = (p > x) ? p : x;
    p = hm_dpp64<0x112>(x); x = (p > x) ? p : x;
    p = hm_dpp64<0x114>(x); x = (p > x) ? p : x;
    p = hm_dpp64<0x118>(x); x = (p > x) ? p : x;
    p = hm_dpp64<0x142>(x); x = (p > x) ? p : x;
    p = hm_dpp64<0x143>(x); x = (p > x) ? p : x;
    u32 lo = (u32)__builtin_amdgcn_readlane((int)(u32)x, 63);
    u32 hi = (u32)__builtin_amdgcn_readlane((int)(u32)(x >> 32), 63);
    return ((ull)hi << 32) | lo;
}

// min of plain keys over the wave's overlay slots (identity MAXK -> ~=0 inert)
__device__ inline ull hm_ov_min(ull a, ull b) {
    ull x = ~a, y = ~b;
    ull z = (x > y) ? x : y;
    return ~hm_wave_max_full64(z);
}

// exact column-min rescan over surviving rows (memory; very rare)
__device__ inline ull hm_rescan(const float* Cb, int t, u32 removed, int l) {
    ull best = 0ull;
#pragma unroll
    for (int i = 0; i < ROWS_PER_LANE; ++i) {
        int r = l + 64 * i;
        bool ok = (r < Q_) && !((removed >> i) & 1u);
        float v = ok ? Cb[(size_t)r * T_ + t] : BIGF;
        ull ik = ok ? hm_ikey(v, r, t) : 0ull;
        best = (ik > best) ? ik : best;
    }
    return ~hm_wave_max_full64(best);
}

// insert exact entry into the owner lane's overlay slot
__device__ inline void hm_ov_insert(ull ins, int l, ull& ovK0, ull& ovK1) {
    int t2 = (int)((u32)ins & 127u);
    int owner = t2 & 63;
    if (t2 < 64) { if (l == owner) ovK0 = ins; }
    else         { if (l == owner) ovK1 = ins; }
}

// ---------------------------------------------------------------------------
// Greedy: ONE WAVE per batch, SORTED-WALK.
// Setup: fold chunk partials -> per-column (top1,top2) plain keys; rank-sort
// the 128 slots (100 live + 28 unique dead sentinels) via LDS count+scatter;
// lane l holds sorted ranks l and 64+l in registers.
// Walk: validity of ranks 0..99 in two uniform 64-bit masks. Per pick:
// head = first valid rank (s_ff1 + 2 readlanes); winner = min(head,
// overlayMin[SGPR]); consume; one ballot detects columns whose cached argmin
// row just died (~11/batch) -> promote top2 (exact) into overlay, or memory
// rescan if both cached rows dead (~1/batch). Exact flat-order semantics:
// column min changes only on argmin-row death (R11 invariant); keys embed
// (value,row,t).
// ---------------------------------------------------------------------------
__global__ __launch_bounds__(64) void hm_greedy_sorted(
    const float* __restrict__ cost,     // [B,Q,T]
    const ull* __restrict__ part,       // [B,CHUNKS,T,2]
    float* __restrict__ out_src,        // [B,N]
    float* __restrict__ out_tgt)        // [B,N]
{
    int b = blockIdx.x;
    int l = threadIdx.x;                // 0..63
    const float* Cb = cost + (size_t)b * Q_ * T_;

    int  t0 = l, t1 = 64 + l;
    bool a1 = (t1 < T_);

    __shared__ ull s_key[128];          // 1 KB
    __shared__ ull s_pay[128];          // 1 KB

    // ---- fold chunk top-2 partials (inverted keys, max == min) ----
    ull i1a = 0ull, i2a = 0ull, i1b = 0ull, i2b = 0ull;
#pragma unroll
    for (int c = 0; c < CHUNKS; ++c) {
        const ull* p0 = part + (((size_t)b * CHUNKS + c) * T_ + t0) * 2;
#pragma unroll
        for (int j = 0; j < 2; ++j) {
            ull cc = p0[j];
            if (cc > i1a) { i2a = i1a; i1a = cc; }
            else if (cc > i2a) i2a = cc;
        }
        if (a1) {
            const ull* p1 = part + (((size_t)b * CHUNKS + c) * T_ + t1) * 2;
#pragma unroll
            for (int j = 0; j < 2; ++j) {
                ull cc = p1[j];
                if (cc > i1b) { i2b = i1b; i1b = cc; }
                else if (cc > i2b) i2b = cc;
            }
        }
    }
    // plain keys; dead columns get unique huge sentinels (> any live key)
    ull keyA = ~i1a, payA = ~i2a;
    ull keyB = a1 ? ~i1b : (0xFFFFFFFFFFFFFF00ull | (ull)(u32)(64 + l));
    ull payB = a1 ? ~i2b : MAXK;

    s_key[l] = keyA;      s_pay[l] = payA;
    s_key[64 + l] = keyB; s_pay[64 + l] = payB;
    __syncthreads();

    // ---- rank by counting (keys unique) ----
    int rank0 = 0, rank1 = 0;
#pragma unroll 4
    for (int j = 0; j < 128; ++j) {
        ull kj = s_key[j];
        rank0 += (kj < keyA) ? 1 : 0;
        rank1 += (kj < keyB) ? 1 : 0;
    }
    __syncthreads();
    s_key[rank0] = keyA; s_pay[rank0] = payA;
    s_key[rank1] = keyB; s_pay[rank1] = payB;
    __syncthreads();

    // ---- gather sorted: lane l holds ranks l and 64+l ----
    ull sk0 = s_key[l],      sp0 = s_pay[l];
    ull sk1 = s_key[64 + l], sp1 = s_pay[64 + l];
    int row0 = (int)(((u32)sk0 >> 7) & 1023u);
    int row1 = (int)(((u32)sk1 >> 7) & 1023u);
    bool v0 = true;              // rank l < 100
    bool v1 = (l < T_ - 64);     // rank 64+l < 100

    ull validLo = ~0ull;                          // ranks 0..63
    ull validHi = (1ull << (T_ - 64)) - 1ull;     // ranks 64..99
    ull ovK0 = MAXK, ovK1 = MAXK;                 // overlay slots (col l, 64+l)
    ull ovMin = MAXK;
    u32 removed = 0u;
    u32 pk0 = 0u, pk1 = 0u;

    for (int k = 0; k < N_; ++k) {
        // ---- head of sorted survivors
        int hr = -1;
        if (validLo)      hr = __ffsll(validLo) - 1;
        else if (validHi) hr = 64 + (__ffsll(validHi) - 1);
        ull headKey = MAXK;
        if (hr >= 0) {
            int hl = hr & 63;
            u32 klo, khi;
            if (hr < 64) {
                klo = (u32)__builtin_amdgcn_readlane((int)(u32)sk0, hl);
                khi = (u32)__builtin_amdgcn_readlane((int)(u32)(sk0 >> 32), hl);
            } else {
                klo = (u32)__builtin_amdgcn_readlane((int)(u32)sk1, hl);
                khi = (u32)__builtin_amdgcn_readlane((int)(u32)(sk1 >> 32), hl);
            }
            headKey = ((ull)khi << 32) | klo;
        }

        bool fromOv = (ovMin < headKey);
        ull wkey = fromOv ? ovMin : headKey;
        u32 wlo = (u32)wkey;
        int t = (int)(wlo & 127u);
        int q = (int)((wlo >> 7) & 1023u);

        // ---- consume winner
        if (fromOv) {
            int owner = t & 63;
            if (t < 64) { if (l == owner) ovK0 = MAXK; }
            else        { if (l == owner) ovK1 = MAXK; }
            ovMin = hm_ov_min(ovK0, ovK1);
        } else {
            if (hr < 64) validLo &= ~(1ull << hr);
            else         validHi &= ~(1ull << (hr - 64));
            int hl = hr & 63;
            if (l == hl) { if (hr < 64) v0 = false; else v1 = false; }
        }

        // ---- record pick; mark removed row
        u32 qt = wlo & 0x1FFFFu;
        if (k < 64) { if (l == k)        pk0 = qt; }
        else        { if (l == (k & 63)) pk1 = qt; }
        if ((q & 63) == l) removed |= 1u << (q >> 6);

        // ---- row-death detection (one ballot)
        bool hit = (v0 && row0 == q) || (v1 && row1 == q);
        hit = hit || ((ovK0 != MAXK) && ((int)(((u32)ovK0 >> 7) & 1023u) == q));
        hit = hit || ((ovK1 != MAXK) && ((int)(((u32)ovK1 >> 7) & 1023u) == q));
        ull bal = __ballot(hit);

        if (bal) {
            // ---- RARE: promote/rescan each affected column
            ull mb = bal;
            while (mb) {
                int p = __ffsll(mb) - 1; mb &= mb - 1;
                // sorted entry 0 of lane p (rank p)
                {
                    int vv = (int)__builtin_amdgcn_readlane(v0 ? 1 : 0, p);
                    int rr = (int)__builtin_amdgcn_readlane(row0, p);
                    if (vv && rr == q) {
                        validLo &= ~(1ull << p);
                        if (l == p) v0 = false;
                        u32 plo = (u32)__builtin_amdgcn_readlane((int)(u32)sp0, p);
                        u32 phi = (u32)__builtin_amdgcn_readlane((int)(u32)(sp0 >> 32), p);
                        ull pay = ((ull)phi << 32) | plo;
                        int r2 = (int)(((u32)pay >> 7) & 1023u);
                        u32 rm = (u32)__builtin_amdgcn_readlane((int)removed, r2 & 63);
                        ull ins = (!((rm >> (r2 >> 6)) & 1u))
                                  ? pay
                                  : hm_rescan(Cb, (int)((u32)pay & 127u), removed, l);
                        hm_ov_insert(ins, l, ovK0, ovK1);
                    }
                }
                // sorted entry 1 of lane p (rank 64+p)
                {
                    int vv = (int)__builtin_amdgcn_readlane(v1 ? 1 : 0, p);
                    int rr = (int)__builtin_amdgcn_readlane(row1, p);
                    if (vv && rr == q) {
                        validHi &= ~(1ull << p);
                        if (l == p) v1 = false;
                        u32 plo = (u32)__builtin_amdgcn_readlane((int)(u32)sp1, p);
                        u32 phi = (u32)__builtin_amdgcn_readlane((int)(u32)(sp1 >> 32), p);
                        ull pay = ((ull)phi << 32) | plo;
                        int r2 = (int)(((u32)pay >> 7) & 1023u);
                        u32 rm = (u32)__builtin_amdgcn_readlane((int)removed, r2 & 63);
                        ull ins = (!((rm >> (r2 >> 6)) & 1u))
                                  ? pay
                                  : hm_rescan(Cb, (int)((u32)pay & 127u), removed, l);
                        hm_ov_insert(ins, l, ovK0, ovK1);
                    }
                }
                // overlay slot 0 of lane p (both cached rows dead -> rescan)
                {
                    u32 klo = (u32)__builtin_amdgcn_readlane((int)(u32)ovK0, p);
                    u32 khi = (u32)__builtin_amdgcn_readlane((int)(u32)(ovK0 >> 32), p);
                    ull ok = ((ull)khi << 32) | klo;
                    if (ok != MAXK && ((int)(((u32)ok >> 7) & 1023u) == q)) {
                        ull ins = hm_rescan(Cb, (int)((u32)ok & 127u), removed, l);
                        hm_ov_insert(ins, l, ovK0, ovK1);   // overwrites same slot
                    }
                }
                // overlay slot 1 of lane p
                {
                    u32 klo = (u32)__builtin_amdgcn_readlane((int)(u32)ovK1, p);
                    u32 khi = (u32)__builtin_amdgcn_readlane((int)(u32)(ovK1 >> 32), p);
                    ull ok = ((ull)khi << 32) | klo;
                    if (ok != MAXK && ((int)(((u32)ok >> 7) & 1023u) == q)) {
                        ull ins = hm_rescan(Cb, (int)((u32)ok & 127u), removed, l);
                        hm_ov_insert(ins, l, ovK0, ovK1);
                    }
                }
            }
            ovMin = hm_ov_min(ovK0, ovK1);
        }
    }

    // ---- coalesced final store of all picks
    float* os = out_src + b * N_;
    float* ot = out_tgt + b * N_;
    os[l] = (float)(pk0 >> 7);
    ot[l] = (float)(pk0 & 127u);
    if (l < N_ - 64) {
        os[64 + l] = (float)(pk1 >> 7);
        ot[64 + l] = (float)(pk1 & 127u);
    }
}

// ---------------------------------------------------------------------------
extern "C" void kernel_launch(void* const* d_in, const int* in_sizes, int n_in,
                              void* d_out, int out_size, void* d_ws, size_t ws_size,
                              hipStream_t stream)
{
    const float* pred_logits = (const float*)d_in[0];  // [B,Q,C]
    const float* pred_boxes  = (const float*)d_in[1];  // [B,Q,4]
    const int*   tgt_labels  = (const int*)d_in[2];    // [B,T]
    const float* tgt_boxes   = (const float*)d_in[3];  // [B,T,4]

    float* out_cost = (float*)d_out;                       // [B,Q,T]
    float* out_src  = out_cost + (size_t)B_ * Q_ * T_;     // [B,N]
    float* out_tgt  = out_src  + (size_t)B_ * N_;          // [B,N]

    ull* part = (ull*)d_ws;                                // [B,CHUNKS,T,2] 2.56 MB

    // 1: fused softmax + cost + column top-2 partials — f32 (R16, unchanged)
    hm_cost_colmin_f32<<<B_ * CHUNKS, 256, 0, stream>>>(pred_logits, pred_boxes,
                                                        tgt_labels, tgt_boxes,
                                                        out_cost, part);

    // 2: greedy — one wave per batch, sorted-walk picks
    hm_greedy_sorted<<<B_, 64, 0, stream>>>(out_cost, part, out_src, out_tgt);
}

// Round 18
// 89.189 us; speedup vs baseline: 1.3259x; 1.1722x over previous
//
#include <hip/hip_runtime.h>
#include <math.h>

#define B_ 64
#define Q_ 900
#define C_ 256
#define T_ 100
#define N_ 100            // min(Q,T)
#define BIGF 1.0e30f
#define ROWS_PER_LANE 15  // ceil(900/64) — rescan striding
#define CHUNKS 25         // row-chunks for colmin partials
#define RPC 36            // rows per chunk

typedef unsigned int u32;
typedef unsigned long long ull;

// ---------------------------------------------------------------------------
// Key scheme:
//   u64 key  = ordf(v)<<18 | stale<<17 | row<<7 | t   (partials / rescan)
//   ikey = ~key (max semantics, identity 0)
// Greedy holds 32-bit split state: v = ordf(val), id = stale<<17|row<<7|t.
// Pick order = lex(value, stale, row, t) == jnp.argmin flat order for fresh.
// ---------------------------------------------------------------------------
__device__ inline u32 hm_ordf(float v) {
    u32 u = __float_as_uint(v);
    return (u & 0x80000000u) ? ~u : (u | 0x80000000u);
}
__device__ inline ull hm_ikey(float v, int r, int t) {
    return ~(((ull)hm_ordf(v) << 18) | ((ull)(u32)r << 7) | (ull)(u32)t);
}

// ---------------------------------------------------------------------------
// Fused cost + column TOP-2 partials — f32 math mirroring the reference
// (VERBATIM from R16/R17; absmax 0.015625, ~34 us measured).
// ---------------------------------------------------------------------------
__global__ __launch_bounds__(256) void hm_cost_colmin_f32(
    const float* __restrict__ logits,   // [B,Q,C]
    const float* __restrict__ pboxes,   // [B,Q,4] cxcywh
    const int*   __restrict__ tlabels,  // [B,T]
    const float* __restrict__ tboxes,   // [B,T,4] cxcywh
    float* __restrict__ cost,           // [B,Q,T]
    ull* __restrict__ part)             // [B,CHUNKS,T,2] inverted top-2 keys
{
    int bc   = blockIdx.x;
    int b    = bc / CHUNKS;
    int c    = bc % CHUNKS;
    int lane = threadIdx.x & 63;
    int wid  = threadIdx.x >> 6;        // 0..3
    int r0   = c * RPC;

    __shared__ float s_exp[4][C_];      // 4 KB
    __shared__ ull   s_part[4][128][2]; // 8 KB

    int ta = lane, tb = 64 + lane;
    bool hb = (tb < T_);
    int laba = tlabels[b * T_ + ta];
    int labb = hb ? tlabels[b * T_ + tb] : 0;
    const float* tba = tboxes + ((size_t)b * T_ + ta) * 4;
    const float* tbb = tboxes + ((size_t)b * T_ + (hb ? tb : 0)) * 4;
    float tcxa = tba[0], tcya = tba[1], twa = tba[2], tha = tba[3];
    float tcxb = tbb[0], tcyb = tbb[1], twb = tbb[2], thb_ = tbb[3];
    float txa1 = tcxa - 0.5f * twa, tya1 = tcya - 0.5f * tha;
    float txa2 = tcxa + 0.5f * twa, tya2 = tcya + 0.5f * tha;
    float txb1 = tcxb - 0.5f * twb, tyb1 = tcyb - 0.5f * thb_;
    float txb2 = tcxb + 0.5f * twb, tyb2 = tcyb + 0.5f * thb_;
    float area2a = fmaxf(txa2 - txa1, 0.0f) * fmaxf(tya2 - tya1, 0.0f);
    float area2b = fmaxf(txb2 - txb1, 0.0f) * fmaxf(tyb2 - tyb1, 0.0f);

    ull ka1 = 0ull, ka2 = 0ull;
    ull kb1 = 0ull, kb2 = 0ull;

    for (int r = r0 + wid; r < r0 + RPC; r += 4) {
        int bq = b * Q_ + r;

        const float* row = logits + (size_t)bq * C_;
        float v[4];
        float m = -INFINITY;
#pragma unroll
        for (int i = 0; i < 4; ++i) {
            v[i] = row[lane + 64 * i];
            m = fmaxf(m, v[i]);
        }
#pragma unroll
        for (int off = 32; off >= 1; off >>= 1)
            m = fmaxf(m, __shfl_xor(m, off, 64));

        float e[4];
        float s = 0.0f;
#pragma unroll
        for (int i = 0; i < 4; ++i) {
            e[i] = expf(v[i] - m);
            s += e[i];
        }
#pragma unroll
        for (int off = 32; off >= 1; off >>= 1)
            s += __shfl_xor(s, off, 64);

#pragma unroll
        for (int i = 0; i < 4; ++i)
            s_exp[wid][lane + 64 * i] = e[i];

        const float* pb = pboxes + (size_t)bq * 4;
        float pcx = pb[0], pcy = pb[1], pw = pb[2], ph = pb[3];
        float px1 = pcx - 0.5f * pw, py1 = pcy - 0.5f * ph;
        float px2 = pcx + 0.5f * pw, py2 = pcy + 0.5f * ph;
        float area1 = fmaxf(px2 - px1, 0.0f) * fmaxf(py2 - py1, 0.0f);

        {
            float prob = s_exp[wid][laba] / s;
            float l1 = fabsf(pcx - tcxa) + fabsf(pcy - tcya) + fabsf(pw - twa) + fabsf(ph - tha);
            float iw = fmaxf(fminf(px2, txa2) - fmaxf(px1, txa1), 0.0f);
            float ih = fmaxf(fminf(py2, tya2) - fmaxf(py1, tya1), 0.0f);
            float inter = iw * ih;
            float uni = area1 + area2a - inter;
            float iou = inter / fmaxf(uni, 1e-6f);
            float ew = fmaxf(fmaxf(px2, txa2) - fminf(px1, txa1), 0.0f);
            float eh = fmaxf(fmaxf(py2, tya2) - fminf(py1, tya1), 0.0f);
            float earea = ew * eh;
            float giou = iou - (earea - uni) / fmaxf(earea, 1e-6f);
            float cf = -prob + 5.0f * l1 - 2.0f * giou;
            cost[(size_t)bq * T_ + ta] = cf;
            ull kk = hm_ikey(cf, r, ta);
            if (kk > ka1) { ka2 = ka1; ka1 = kk; }
            else if (kk > ka2) ka2 = kk;
        }
        if (hb) {
            float prob = s_exp[wid][labb] / s;
            float l1 = fabsf(pcx - tcxb) + fabsf(pcy - tcyb) + fabsf(pw - twb) + fabsf(ph - thb_);
            float iw = fmaxf(fminf(px2, txb2) - fmaxf(px1, txb1), 0.0f);
            float ih = fmaxf(fminf(py2, tyb2) - fmaxf(py1, tyb1), 0.0f);
            float inter = iw * ih;
            float uni = area1 + area2b - inter;
            float iou = inter / fmaxf(uni, 1e-6f);
            float ew = fmaxf(fmaxf(px2, txb2) - fminf(px1, txb1), 0.0f);
            float eh = fmaxf(fmaxf(py2, tyb2) - fminf(py1, tyb1), 0.0f);
            float earea = ew * eh;
            float giou = iou - (earea - uni) / fmaxf(earea, 1e-6f);
            float cf = -prob + 5.0f * l1 - 2.0f * giou;
            cost[(size_t)bq * T_ + tb] = cf;
            ull kk = hm_ikey(cf, r, tb);
            if (kk > kb1) { kb2 = kb1; kb1 = kk; }
            else if (kk > kb2) kb2 = kk;
        }
    }

    s_part[wid][lane][0]      = ka1;
    s_part[wid][lane][1]      = ka2;
    s_part[wid][64 + lane][0] = kb1;
    s_part[wid][64 + lane][1] = kb2;
    __syncthreads();
    int tid = threadIdx.x;
    if (tid < T_) {
        ull b1 = 0ull, b2 = 0ull;
#pragma unroll
        for (int w = 0; w < 4; ++w) {
#pragma unroll
            for (int j = 0; j < 2; ++j) {
                ull cc = s_part[w][tid][j];
                if (cc > b1) { b2 = b1; b1 = cc; }
                else if (cc > b2) b2 = cc;
            }
        }
        ull* dst = part + (((size_t)b * CHUNKS + c) * T_ + tid) * 2;
        dst[0] = b1;
        dst[1] = b2;
    }
}

// ---------------------------------------------------------------------------
// DPP helpers.
// ---------------------------------------------------------------------------
__device__ inline u32 hm_umax32(u32 a, u32 b) { return a > b ? a : b; }

__device__ inline u32 hm_wave_max_u32_full(u32 y) {
    y = hm_umax32(y, (u32)__builtin_amdgcn_update_dpp(0, (int)y, 0x111, 0xF, 0xF, false));
    y = hm_umax32(y, (u32)__builtin_amdgcn_update_dpp(0, (int)y, 0x112, 0xF, 0xF, false));
    y = hm_umax32(y, (u32)__builtin_amdgcn_update_dpp(0, (int)y, 0x114, 0xF, 0xF, false));
    y = hm_umax32(y, (u32)__builtin_amdgcn_update_dpp(0, (int)y, 0x118, 0xF, 0xF, false));
    y = hm_umax32(y, (u32)__builtin_amdgcn_update_dpp(0, (int)y, 0x142, 0xF, 0xF, false));
    y = hm_umax32(y, (u32)__builtin_amdgcn_update_dpp(0, (int)y, 0x143, 0xF, 0xF, false));
    return (u32)__builtin_amdgcn_readlane((int)y, 63);
}

template <int CTRL>
__device__ inline ull hm_dpp64(ull x) {
    u32 lo = (u32)x, hi = (u32)(x >> 32);
    lo = (u32)__builtin_amdgcn_update_dpp(0, (int)lo, CTRL, 0xF, 0xF, false);
    hi = (u32)__builtin_amdgcn_update_dpp(0, (int)hi, CTRL, 0xF, 0xF, false);
    return ((ull)hi << 32) | lo;
}
__device__ inline ull hm_wave_max_full64(ull x) {     // rare rescan path only
    ull p;
    p = hm_dpp64<0x111>(x); x = (p > x) ? p : x;
    p = hm_dpp64<0x112>(x); x = (p > x) ? p : x;
    p = hm_dpp64<0x114>(x); x = (p > x) ? p : x;
    p = hm_dpp64<0x118>(x); x = (p > x) ? p : x;
    p = hm_dpp64<0x142>(x); x = (p > x) ? p : x;
    p = hm_dpp64<0x143>(x); x = (p > x) ? p : x;
    u32 lo = (u32)__builtin_amdgcn_readlane((int)(u32)x, 63);
    u32 hi = (u32)__builtin_amdgcn_readlane((int)(u32)(x >> 32), 63);
    return ((ull)hi << 32) | lo;
}

// ---------------------------------------------------------------------------
// Greedy: ONE WAVE per batch — R13's two-phase 32-bit structure (measured
// best at 45 us), with pick registers + single coalesced final store.
//   phase1: 6-stage DPP max of ~v -> winner value (readlane 63)
//   phase2: 6-stage DPP max of ~id among value-ties -> winner id
//   branch-free top-2 maintenance; stale winner (bit17) -> rescan, retry k.
// ---------------------------------------------------------------------------
__global__ __launch_bounds__(64) void hm_greedy_32(
    const float* __restrict__ cost,     // [B,Q,T]
    const ull* __restrict__ part,       // [B,CHUNKS,T,2]
    float* __restrict__ out_src,        // [B,N]
    float* __restrict__ out_tgt)        // [B,N]
{
    int b = blockIdx.x;
    int l = threadIdx.x;                // 0..63
    const float* Cb = cost + (size_t)b * Q_ * T_;

    int  t0 = l, t1 = 64 + l;
    bool a1 = (t1 < T_);

    // ---- phase 0: fold chunk top-2 partials (u64), split to 32-bit ----
    ull c1a = 0ull, c2a = 0ull, c1b = 0ull, c2b = 0ull;
#pragma unroll
    for (int c = 0; c < CHUNKS; ++c) {
        const ull* p0 = part + (((size_t)b * CHUNKS + c) * T_ + t0) * 2;
#pragma unroll
        for (int j = 0; j < 2; ++j) {
            ull cc = p0[j];
            if (cc > c1a) { c2a = c1a; c1a = cc; }
            else if (cc > c2a) c2a = cc;
        }
        if (a1) {
            const ull* p1 = part + (((size_t)b * CHUNKS + c) * T_ + t1) * 2;
#pragma unroll
            for (int j = 0; j < 2; ++j) {
                ull cc = p1[j];
                if (cc > c1b) { c2b = c1b; c1b = cc; }
                else if (cc > c2b) c2b = cc;
            }
        }
    }
    // split: key = ~ikey; v = key>>18, id = key & 0x3FFFF
    u32 va  = (u32)((~c1a) >> 18), ida  = (u32)(~c1a) & 0x3FFFFu;
    u32 v2a = (u32)((~c2a) >> 18), id2a = (u32)(~c2a) & 0x3FFFFu;
    u32 vb  = a1 ? (u32)((~c1b) >> 18) : 0xFFFFFFFFu;
    u32 idb = a1 ? ((u32)(~c1b) & 0x3FFFFu) : 0x3FFFFu;
    u32 v2b = a1 ? (u32)((~c2b) >> 18) : 0xFFFFFFFFu;
    u32 id2b = a1 ? ((u32)(~c2b) & 0x3FFFFu) : 0x3FFFFu;

    unsigned removed = 0u;              // bit i => row (l + 64*i) removed
    u32 pk0 = 0u, pk1 = 0u;             // pick registers: lane k&63 holds pick k

    int k = 0;
    while (k < N_) {
        // ---- phase 1: wave-min of value (as max of ~v)
        u32 ya = ~va, yb = ~vb;
        u32 winy = hm_wave_max_u32_full(ya > yb ? ya : yb);

        // ---- phase 2: wave-min of id among value-ties (as max of ~id)
        u32 za = (ya == winy) ? ~ida : 0u;
        u32 zb = (yb == winy) ? ~idb : 0u;
        u32 winz = hm_wave_max_u32_full(za > zb ? za : zb);
        u32 winid = (~winz) & 0x3FFFFu;

        int t = (int)(winid & 127u);
        int q = (int)((winid >> 7) & 1023u);

        if (winid & 0x20000u) {
            // ---- RARE: stale lower-bound won -> rescan column t, retry k
            ull b1 = 0ull, b2 = 0ull;
#pragma unroll
            for (int i = 0; i < ROWS_PER_LANE; ++i) {
                int r = l + 64 * i;
                bool ok = (r < Q_) && !((removed >> i) & 1u);
                float v = ok ? Cb[(size_t)r * T_ + t] : BIGF;
                ull ik = ok ? hm_ikey(v, r, t) : 0ull;
                if (ik > b1) { b2 = b1; b1 = ik; }
                else if (ik > b2) b2 = ik;
            }
            ull w1 = hm_wave_max_full64(b1);
            ull alt = (b1 == w1) ? b2 : b1;   // keys unique
            ull w2 = hm_wave_max_full64(alt);
            if (t0 == t) {
                va  = (u32)((~w1) >> 18); ida  = (u32)(~w1) & 0x3FFFFu;
                v2a = (u32)((~w2) >> 18); id2a = (u32)(~w2) & 0x3FFFFu;
            }
            if (t1 == t) {
                vb  = (u32)((~w1) >> 18); idb  = (u32)(~w1) & 0x3FFFFu;
                v2b = (u32)((~w2) >> 18); id2b = (u32)(~w2) & 0x3FFFFu;
            }
            continue;
        }

        // ---- accept pick into registers (lane k&63)
        u32 qt = winid & 0x1FFFFu;
        if (k < 64) { if (l == k)        pk0 = qt; }
        else        { if (l == (k & 63)) pk1 = qt; }
        if ((q & 63) == l) removed |= 1u << (q >> 6);

        // ---- branch-free top-2 maintenance (all 32-bit), column a
        {
            bool die1 = (((ida  >> 7) & 1023u) == (u32)q);
            bool die2 = (((id2a >> 7) & 1023u) == (u32)q);
            u32 nva  = die1 ? v2a  : va;
            u32 nida = die1 ? id2a : ida;
            u32 nid2 = (die1 || die2) ? (id2a | 0x20000u) : id2a;
            bool kill = (t0 == t);
            va   = kill ? 0xFFFFFFFFu : nva;
            ida  = kill ? 0x3FFFFu    : nida;
            v2a  = kill ? 0xFFFFFFFFu : v2a;
            id2a = kill ? 0x3FFFFu    : nid2;
        }
        // ---- column b
        {
            bool die1 = (((idb  >> 7) & 1023u) == (u32)q);
            bool die2 = (((id2b >> 7) & 1023u) == (u32)q);
            u32 nvb  = die1 ? v2b  : vb;
            u32 nidb = die1 ? id2b : idb;
            u32 nid2 = (die1 || die2) ? (id2b | 0x20000u) : id2b;
            bool kill = (t1 == t);
            vb   = kill ? 0xFFFFFFFFu : nvb;
            idb  = kill ? 0x3FFFFu    : nidb;
            v2b  = kill ? 0xFFFFFFFFu : v2b;
            id2b = kill ? 0x3FFFFu    : nid2;
        }

        ++k;
    }

    // ---- coalesced final store of all picks
    float* os = out_src + b * N_;
    float* ot = out_tgt + b * N_;
    os[l] = (float)(pk0 >> 7);
    ot[l] = (float)(pk0 & 127u);
    if (l < N_ - 64) {
        os[64 + l] = (float)(pk1 >> 7);
        ot[64 + l] = (float)(pk1 & 127u);
    }
}

// ---------------------------------------------------------------------------
extern "C" void kernel_launch(void* const* d_in, const int* in_sizes, int n_in,
                              void* d_out, int out_size, void* d_ws, size_t ws_size,
                              hipStream_t stream)
{
    const float* pred_logits = (const float*)d_in[0];  // [B,Q,C]
    const float* pred_boxes  = (const float*)d_in[1];  // [B,Q,4]
    const int*   tgt_labels  = (const int*)d_in[2];    // [B,T]
    const float* tgt_boxes   = (const float*)d_in[3];  // [B,T,4]

    float* out_cost = (float*)d_out;                       // [B,Q,T]
    float* out_src  = out_cost + (size_t)B_ * Q_ * T_;     // [B,N]
    float* out_tgt  = out_src  + (size_t)B_ * N_;          // [B,N]

    ull* part = (ull*)d_ws;                                // [B,CHUNKS,T,2] 2.56 MB

    // 1: fused softmax + cost + column top-2 partials — f32 (R16, unchanged)
    hm_cost_colmin_f32<<<B_ * CHUNKS, 256, 0, stream>>>(pred_logits, pred_boxes,
                                                        tgt_labels, tgt_boxes,
                                                        out_cost, part);

    // 2: greedy — one wave per batch, R13 two-phase DPP rounds (best measured)
    hm_greedy_32<<<B_, 64, 0, stream>>>(out_cost, part, out_src, out_tgt);
}